// Round 1
// baseline (2037.466 us; speedup 1.0000x reference)
//
#include <hip/hip_runtime.h>
#include <math.h>

#define N_SAMPLES 131072
#define NDIM 512
#define NCOMP 256
#define NCLASS 8
#define NBIN 100
#define ROWS 32
#define BK 16

// Fused kernel: one block = 32 rows.
// Phase 1: data0(32x256) = data(32x512) @ wT(512x256), tiled fp32 VALU GEMM.
// Phase 2: per-element RQ spline (class-routed), delta = y - x stored in LDS,
//          logj written per row (block owns entire rows -> no atomics).
// Phase 3: out(32x512) = data + delta(32x256) @ wT^T(256x512).
__global__ __launch_bounds__(256) void cst_fused(
    const float* __restrict__ data,
    const float* __restrict__ wT,
    const float* __restrict__ kx,
    const float* __restrict__ ky,
    const float* __restrict__ kd,
    const int*   __restrict__ label,
    float* __restrict__ out,
    float* __restrict__ logj)
{
  __shared__ float As[ROWS * 17];        // 32 x 16 (+1 pad)
  __shared__ float Bs[BK * 260];         // 16 x 256 (+4 pad, keeps 16B align)
  __shared__ float deltaS[ROWS * NCOMP]; // 32 x 256

  const int t  = threadIdx.x;
  const int tx = t & 31;   // 0..31  -> 8 comps each (tx*8+j)
  const int ty = t >> 5;   // 0..7   -> 4 rows each (ty*4+i)
  const int rowBase = blockIdx.x * ROWS;

  // ---------------- Phase 1: data0 = data @ wT ----------------
  float acc[4][8];
  #pragma unroll
  for (int i = 0; i < 4; ++i)
    #pragma unroll
    for (int j = 0; j < 8; ++j) acc[i][j] = 0.f;

  for (int k0 = 0; k0 < NDIM; k0 += BK) {
    __syncthreads();
    if (t < 128) {                      // stage As: 32 rows x 16 k
      const int r  = t >> 2;
      const int kq = (t & 3) * 4;
      const float4 v = *(const float4*)(data + (size_t)(rowBase + r) * NDIM + k0 + kq);
      float* dst = &As[r * 17 + kq];
      dst[0] = v.x; dst[1] = v.y; dst[2] = v.z; dst[3] = v.w;
    }
    {                                   // stage Bs[kk][c] = wT[k0+kk][c]
      const int kk = t >> 4;            // 0..15
      const int cb = (t & 15) * 4;      // 0..60
      #pragma unroll
      for (int jj = 0; jj < 4; ++jj) {
        const float4 v = *(const float4*)(wT + (size_t)(k0 + kk) * NCOMP + cb + 64 * jj);
        float* dst = &Bs[kk * 260 + cb + 64 * jj];
        dst[0] = v.x; dst[1] = v.y; dst[2] = v.z; dst[3] = v.w;
      }
    }
    __syncthreads();
    #pragma unroll
    for (int kk = 0; kk < BK; ++kk) {
      const float a0 = As[(ty * 4 + 0) * 17 + kk];
      const float a1 = As[(ty * 4 + 1) * 17 + kk];
      const float a2 = As[(ty * 4 + 2) * 17 + kk];
      const float a3 = As[(ty * 4 + 3) * 17 + kk];
      const float* bp = &Bs[kk * 260 + tx * 8];
      float b[8];
      #pragma unroll
      for (int j = 0; j < 8; ++j) b[j] = bp[j];
      #pragma unroll
      for (int j = 0; j < 8; ++j) {
        acc[0][j] = fmaf(a0, b[j], acc[0][j]);
        acc[1][j] = fmaf(a1, b[j], acc[1][j]);
        acc[2][j] = fmaf(a2, b[j], acc[2][j]);
        acc[3][j] = fmaf(a3, b[j], acc[3][j]);
      }
    }
  }
  __syncthreads();
  #pragma unroll
  for (int i = 0; i < 4; ++i) {        // spill data0 tile to LDS
    float* dst = &deltaS[(ty * 4 + i) * NCOMP + tx * 8];
    #pragma unroll
    for (int j = 0; j < 8; ++j) dst[j] = acc[i][j];
  }
  __syncthreads();

  // ---------------- Phase 2: RQ spline, in place ----------------
  {
    const int row = t >> 3;                       // 0..31 (8 threads per row)
    const int lab = label[rowBase + row];
    const size_t tb = (size_t)lab * NCOMP * NBIN;
    float ldsum = 0.f;
    #pragma unroll 1
    for (int q = 0; q < 32; ++q) {
      const int comp = (t & 7) * 32 + ((q + t) & 31);   // swizzle: avoid bank collision
      const float x = deltaS[row * NCOMP + comp];
      const float* xk = kx + tb + (size_t)comp * NBIN;
      const float* yk = ky + tb + (size_t)comp * NBIN;
      const float* dk = kd + tb + (size_t)comp * NBIN;
      // searchsorted side='left': first idx with xk[idx] >= x
      int lo = 0, hi = NBIN;
      while (lo < hi) {
        const int mid = (lo + hi) >> 1;
        if (xk[mid] < x) lo = mid + 1; else hi = mid;
      }
      float y, ld;
      if (lo == 0) {
        const float d0 = dk[0];
        y  = yk[0] + d0 * (x - xk[0]);
        ld = logf(d0);
      } else if (lo == NBIN) {
        const float d1 = dk[NBIN - 1];
        y  = yk[NBIN - 1] + d1 * (x - xk[NBIN - 1]);
        ld = logf(d1);
      } else {
        const int k = lo - 1;
        const float x0 = xk[k], x1 = xk[k + 1];
        const float y0 = yk[k], y1 = yk[k + 1];
        const float d0 = dk[k], d1 = dk[k + 1];
        const float w  = x1 - x0;
        const float s  = (y1 - y0) / w;
        float xi = (x - x0) / w;
        xi = fminf(fmaxf(xi, 0.f), 1.f);
        const float xi1 = 1.f - xi;
        const float denom = s + (d0 + d1 - 2.f * s) * xi * xi1;
        y  = y0 + (y1 - y0) * (s * xi * xi + d0 * xi * xi1) / denom;
        ld = 2.f * logf(s)
           + logf(d1 * xi * xi + 2.f * s * xi * xi1 + d0 * xi1 * xi1)
           - 2.f * logf(denom);
      }
      deltaS[row * NCOMP + comp] = y - x;   // delta = out0 - data0
      ldsum += ld;
    }
    ldsum += __shfl_down(ldsum, 4, 8);
    ldsum += __shfl_down(ldsum, 2, 8);
    ldsum += __shfl_down(ldsum, 1, 8);
    if ((t & 7) == 0) logj[rowBase + row] = ldsum;
  }

  // ---------------- Phase 3: out = data + delta @ wT^T ----------------
  for (int g = 0; g < 2; ++g) {
    const int colBase = g * 256;
    float o[4][8];
    #pragma unroll
    for (int i = 0; i < 4; ++i)
      #pragma unroll
      for (int j = 0; j < 8; ++j) o[i][j] = 0.f;

    for (int kb = 0; kb < NCOMP; kb += BK) {
      __syncthreads();
      {   // stage Bs[kk][c] = wT^T[kb+kk][colBase+c] = wT[colBase+c][kb+kk]
        const int kq = (t & 3) * 4;    // 0,4,8,12
        const int cb = t >> 2;         // 0..63
        #pragma unroll
        for (int jj = 0; jj < 4; ++jj) {
          const int c = cb + 64 * jj;
          const float4 v = *(const float4*)(wT + (size_t)(colBase + c) * NCOMP + kb + kq);
          Bs[(kq + 0) * 260 + c] = v.x;
          Bs[(kq + 1) * 260 + c] = v.y;
          Bs[(kq + 2) * 260 + c] = v.z;
          Bs[(kq + 3) * 260 + c] = v.w;
        }
      }
      __syncthreads();
      #pragma unroll
      for (int kk = 0; kk < BK; ++kk) {
        const float a0 = deltaS[(ty * 4 + 0) * NCOMP + kb + kk];
        const float a1 = deltaS[(ty * 4 + 1) * NCOMP + kb + kk];
        const float a2 = deltaS[(ty * 4 + 2) * NCOMP + kb + kk];
        const float a3 = deltaS[(ty * 4 + 3) * NCOMP + kb + kk];
        const float* bp = &Bs[kk * 260 + tx * 8];
        float b[8];
        #pragma unroll
        for (int j = 0; j < 8; ++j) b[j] = bp[j];
        #pragma unroll
        for (int j = 0; j < 8; ++j) {
          o[0][j] = fmaf(a0, b[j], o[0][j]);
          o[1][j] = fmaf(a1, b[j], o[1][j]);
          o[2][j] = fmaf(a2, b[j], o[2][j]);
          o[3][j] = fmaf(a3, b[j], o[3][j]);
        }
      }
    }
    #pragma unroll
    for (int i = 0; i < 4; ++i) {
      const size_t base = (size_t)(rowBase + ty * 4 + i) * NDIM + colBase + tx * 8;
      const float4 d0 = *(const float4*)(data + base);
      const float4 d1 = *(const float4*)(data + base + 4);
      float4 r0, r1;
      r0.x = d0.x + o[i][0]; r0.y = d0.y + o[i][1];
      r0.z = d0.z + o[i][2]; r0.w = d0.w + o[i][3];
      r1.x = d1.x + o[i][4]; r1.y = d1.y + o[i][5];
      r1.z = d1.z + o[i][6]; r1.w = d1.w + o[i][7];
      *(float4*)(out + base)     = r0;
      *(float4*)(out + base + 4) = r1;
    }
  }
}

extern "C" void kernel_launch(void* const* d_in, const int* in_sizes, int n_in,
                              void* d_out, int out_size, void* d_ws, size_t ws_size,
                              hipStream_t stream) {
  const float* data = (const float*)d_in[0];
  const float* wT   = (const float*)d_in[1];
  const float* kx   = (const float*)d_in[2];
  const float* ky   = (const float*)d_in[3];
  const float* kd   = (const float*)d_in[4];
  const int*   lab  = (const int*)d_in[5];
  float* out  = (float*)d_out;
  float* lj   = out + (size_t)N_SAMPLES * NDIM;   // outputs concatenated: out, logj
  dim3 grid(N_SAMPLES / ROWS);
  cst_fused<<<grid, 256, 0, stream>>>(data, wT, kx, ky, kd, lab, out, lj);
}